// Round 2
// baseline (288.462 us; speedup 1.0000x reference)
//
#include <hip/hip_runtime.h>
#include <hip/hip_bf16.h>

// DilatedAttention (b=4, n=8192, d=1024, w=2048, r=4):
// 16 independent 512x512 self-attentions at d=1024 over gathered tokens
// off + 4*j per segment. alphas==1 (idx unique), so output = scatter(att).
//
// R2: single fused attention kernel (QK + softmax + PV + scatter + zero-fill).
// S never touches global memory. GEMM operands are read directly from
// L2-resident xg/xgT as MFMA fragments (no LDS staging, no K-loop barriers).
// LDS holds only P (32x512 bf16, XOR-swizzled) + softmax partials.
// Grid: 16 segs x 16 bands of 32 q-rows = 256 blocks x 512 thr (8 waves).
// seg -> XCD mapping (bid&7) keeps each XCD's L2 on 2 segments (~4 MB).

typedef __bf16 bf16_t;
typedef __bf16 bf16x8 __attribute__((ext_vector_type(8)));
typedef float floatx4 __attribute__((ext_vector_type(4)));

#define D_MODEL 1024
#define SEG_W   2048
#define RATE    4
#define M_SUB   512          // tokens per segment after dilation (w/r)
#define NTOK    8192
#define NSEGT   16           // batch(4) * segments(4)
#define XG_ELEMS ((long)NSEGT * M_SUB * D_MODEL)

// ---------------------------------------------------------------------------
// K1: gather x[b, s*2048 + off + 4i, :] -> xg bf16 [seg][i][d]
//                                       -> xgT bf16 [seg][d][i]
// ---------------------------------------------------------------------------
__global__ __launch_bounds__(256) void gather_kernel(
    const float* __restrict__ x, const int* __restrict__ hidp,
    bf16_t* __restrict__ xg, bf16_t* __restrict__ xgT)
{
    const int off = ((hidp[0] % RATE) + RATE) % RATE;
    const int bid = blockIdx.x;
    const int seg = bid >> 7;          // 0..15
    const int rem = bid & 127;
    const int it  = rem >> 4;          // i-tile 0..7
    const int dt  = rem & 15;          // d-tile 0..15
    const int b   = seg >> 2, s = seg & 3;

    __shared__ ushort tile[64][65];

    const int t  = threadIdx.x;
    const int r  = t >> 2;             // 0..63
    const int cq = (t & 3) << 4;       // 0,16,32,48

    union U8 { bf16x8 v; ushort u[8]; };

    {
        const int  i   = it * 64 + r;
        const long tok = (long)s * SEG_W + off + 4L * i;
        const float* src = x + ((long)b * NTOK + tok) * D_MODEL + dt * 64 + cq;
        float4 f0 = ((const float4*)src)[0];
        float4 f1 = ((const float4*)src)[1];
        float4 f2 = ((const float4*)src)[2];
        float4 f3 = ((const float4*)src)[3];
        U8 lo, hi;
        lo.v[0]=(bf16_t)f0.x; lo.v[1]=(bf16_t)f0.y; lo.v[2]=(bf16_t)f0.z; lo.v[3]=(bf16_t)f0.w;
        lo.v[4]=(bf16_t)f1.x; lo.v[5]=(bf16_t)f1.y; lo.v[6]=(bf16_t)f1.z; lo.v[7]=(bf16_t)f1.w;
        hi.v[0]=(bf16_t)f2.x; hi.v[1]=(bf16_t)f2.y; hi.v[2]=(bf16_t)f2.z; hi.v[3]=(bf16_t)f2.w;
        hi.v[4]=(bf16_t)f3.x; hi.v[5]=(bf16_t)f3.y; hi.v[6]=(bf16_t)f3.z; hi.v[7]=(bf16_t)f3.w;
        bf16_t* dstg = xg + ((long)seg * M_SUB + i) * D_MODEL + dt * 64 + cq;
        *(bf16x8*)(dstg)     = lo.v;
        *(bf16x8*)(dstg + 8) = hi.v;
        #pragma unroll
        for (int j = 0; j < 8; ++j) { tile[r][cq + j] = lo.u[j]; tile[r][cq + 8 + j] = hi.u[j]; }
    }
    __syncthreads();
    {
        const int dc = r;
        const int iq = cq;
        U8 o0, o1;
        #pragma unroll
        for (int j = 0; j < 8; ++j) { o0.u[j] = tile[iq + j][dc]; o1.u[j] = tile[iq + 8 + j][dc]; }
        bf16_t* dstT = xgT + ((long)seg * D_MODEL + dt * 64 + dc) * M_SUB + it * 64 + iq;
        *(bf16x8*)(dstT)     = o0.v;
        *(bf16x8*)(dstT + 8) = o1.v;
    }
}

// ---------------------------------------------------------------------------
// K2: fused attention. One block = one (seg, 32-row q-band).
// Wave w: QK cols w*64..+64 (acc_s[2][4]); PV d-slice w*128..+128 (acc_o[2][8]).
// ---------------------------------------------------------------------------
__global__ __launch_bounds__(512) void attn_kernel(
    const bf16_t* __restrict__ xg, const bf16_t* __restrict__ xgT,
    const int* __restrict__ hidp, float* __restrict__ out)
{
    const int off  = ((hidp[0] % RATE) + RATE) % RATE;
    const int bid0 = blockIdx.x;
    const int sub  = bid0 >> 3;                 // 0..31
    const int seg  = (bid0 & 7) * 2 + (sub >> 4);  // seg->XCD locality
    const int band = sub & 15;                  // q-band within segment
    const int b = seg >> 2, s = seg & 3;

    const int tid  = threadIdx.x;
    const int w    = tid >> 6;                  // wave 0..7
    const int lane = tid & 63;
    const int l16  = lane & 15;
    const int quad = lane >> 4;

    __shared__ alignas(16) bf16_t P_lds[32 * 512];   // 32 KB, XOR-swizzled
    __shared__ float redmax[8][32];
    __shared__ float redsum[8][32];

    const bf16_t* xs  = xg + (long)seg * M_SUB * D_MODEL;
    // Q fragment row pointers (A operand): rows band*32 + {l16, 16+l16}
    const bf16_t* qa0 = xs + (long)(band * 32 + l16) * D_MODEL + quad * 8;
    const bf16_t* qa1 = qa0 + 16 * D_MODEL;
    // K fragment row pointers (B operand): tokens w*64 + n*16 + l16
    const bf16_t* kb0 = xs + (long)(w * 64 + l16) * D_MODEL + quad * 8;
    const bf16_t* kb1 = kb0 + 16 * D_MODEL;
    const bf16_t* kb2 = kb0 + 32 * D_MODEL;
    const bf16_t* kb3 = kb0 + 48 * D_MODEL;

    floatx4 acc_s[2][4];
    #pragma unroll
    for (int m = 0; m < 2; ++m)
        #pragma unroll
        for (int n = 0; n < 4; ++n) acc_s[m][n] = (floatx4){0.f, 0.f, 0.f, 0.f};

    auto lqk = [&](int st, bf16x8 (&A)[2], bf16x8 (&B)[4]) {
        const int o = st * 32;
        A[0] = *(const bf16x8*)(qa0 + o); A[1] = *(const bf16x8*)(qa1 + o);
        B[0] = *(const bf16x8*)(kb0 + o); B[1] = *(const bf16x8*)(kb1 + o);
        B[2] = *(const bf16x8*)(kb2 + o); B[3] = *(const bf16x8*)(kb3 + o);
    };
    auto mqk = [&](bf16x8 (&A)[2], bf16x8 (&B)[4]) {
        #pragma unroll
        for (int m = 0; m < 2; ++m)
            #pragma unroll
            for (int n = 0; n < 4; ++n)
                acc_s[m][n] = __builtin_amdgcn_mfma_f32_16x16x32_bf16(A[m], B[n], acc_s[m][n], 0, 0, 0);
    };

    {   // QK: 32 K-steps of 32 over d, depth-1 ping-pong prefetch
        bf16x8 aP[2], bP[4], aN[2], bN[4];
        lqk(0, aP, bP);
        #pragma unroll 4
        for (int st = 0; st < 32; st += 2) {
            lqk(st + 1, aN, bN);
            mqk(aP, bP);
            if (st + 2 < 32) lqk(st + 2, aP, bP);
            mqk(aN, bN);
        }
    }

    // ---- softmax on f32 scores (rows: m*16 + quad*4 + rg; cols: wave slice)
    #pragma unroll
    for (int m = 0; m < 2; ++m)
        #pragma unroll
        for (int n = 0; n < 4; ++n)
            #pragma unroll
            for (int rg = 0; rg < 4; ++rg) acc_s[m][n][rg] *= 0.03125f;  // 1/sqrt(1024)

    float mx[2][4];
    #pragma unroll
    for (int m = 0; m < 2; ++m)
        #pragma unroll
        for (int rg = 0; rg < 4; ++rg)
            mx[m][rg] = fmaxf(fmaxf(acc_s[m][0][rg], acc_s[m][1][rg]),
                              fmaxf(acc_s[m][2][rg], acc_s[m][3][rg]));
    #pragma unroll
    for (int d = 1; d < 16; d <<= 1)
        #pragma unroll
        for (int m = 0; m < 2; ++m)
            #pragma unroll
            for (int rg = 0; rg < 4; ++rg)
                mx[m][rg] = fmaxf(mx[m][rg], __shfl_xor(mx[m][rg], d, 64));
    if (l16 == 0) {
        #pragma unroll
        for (int m = 0; m < 2; ++m)
            #pragma unroll
            for (int rg = 0; rg < 4; ++rg)
                redmax[w][m * 16 + quad * 4 + rg] = mx[m][rg];
    }
    __syncthreads();
    float gm[2][4];
    #pragma unroll
    for (int m = 0; m < 2; ++m)
        #pragma unroll
        for (int rg = 0; rg < 4; ++rg) {
            const int row = m * 16 + quad * 4 + rg;
            float g = redmax[0][row];
            #pragma unroll
            for (int ww = 1; ww < 8; ++ww) g = fmaxf(g, redmax[ww][row]);
            gm[m][rg] = g;
        }
    float sm[2][4] = {{0.f,0.f,0.f,0.f},{0.f,0.f,0.f,0.f}};
    #pragma unroll
    for (int m = 0; m < 2; ++m)
        #pragma unroll
        for (int n = 0; n < 4; ++n)
            #pragma unroll
            for (int rg = 0; rg < 4; ++rg) {
                const float e = __expf(acc_s[m][n][rg] - gm[m][rg]);
                acc_s[m][n][rg] = e;
                sm[m][rg] += e;
            }
    #pragma unroll
    for (int d = 1; d < 16; d <<= 1)
        #pragma unroll
        for (int m = 0; m < 2; ++m)
            #pragma unroll
            for (int rg = 0; rg < 4; ++rg)
                sm[m][rg] += __shfl_xor(sm[m][rg], d, 64);
    if (l16 == 0) {
        #pragma unroll
        for (int m = 0; m < 2; ++m)
            #pragma unroll
            for (int rg = 0; rg < 4; ++rg)
                redsum[w][m * 16 + quad * 4 + rg] = sm[m][rg];
    }
    __syncthreads();
    float iv[2][4];
    #pragma unroll
    for (int m = 0; m < 2; ++m)
        #pragma unroll
        for (int rg = 0; rg < 4; ++rg) {
            const int row = m * 16 + quad * 4 + rg;
            float t = redsum[0][row];
            #pragma unroll
            for (int ww = 1; ww < 8; ++ww) t += redsum[ww][row];
            iv[m][rg] = 1.f / t;
        }

    // ---- P -> bf16 -> swizzled LDS: chunk c of row r stored at c^(r&7)
    #pragma unroll
    for (int m = 0; m < 2; ++m)
        #pragma unroll
        for (int rg = 0; rg < 4; ++rg) {
            const int row = m * 16 + quad * 4 + rg;
            const float f = iv[m][rg];
            #pragma unroll
            for (int n = 0; n < 4; ++n) {
                const int col = w * 64 + n * 16 + l16;
                const int sw  = (((col >> 3) ^ (row & 7)) << 3) + (col & 7);
                P_lds[row * 512 + sw] = (bf16_t)(acc_s[m][n][rg] * f);
            }
        }
    __syncthreads();

    // ---- PV: out rows band*32.., d-slice w*128..+128; K over 512 tokens
    floatx4 acc_o[2][8];
    #pragma unroll
    for (int m = 0; m < 2; ++m)
        #pragma unroll
        for (int n = 0; n < 8; ++n) acc_o[m][n] = (floatx4){0.f, 0.f, 0.f, 0.f};

    const bf16_t* vb = xgT + ((long)seg * D_MODEL + w * 128 + l16) * M_SUB + quad * 8;

    auto lpv = [&](int kt, bf16x8 (&A)[2], bf16x8 (&B)[8]) {
        #pragma unroll
        for (int m = 0; m < 2; ++m) {
            const int row = m * 16 + l16;
            const int ch  = (kt * 4 + quad) ^ (l16 & 7);
            A[m] = *(const bf16x8*)&P_lds[row * 512 + ch * 8];
        }
        const int ko = kt * 32;
        #pragma unroll
        for (int n = 0; n < 8; ++n)
            B[n] = *(const bf16x8*)(vb + (long)n * 16 * M_SUB + ko);
    };
    auto mpv = [&](bf16x8 (&A)[2], bf16x8 (&B)[8]) {
        #pragma unroll
        for (int m = 0; m < 2; ++m)
            #pragma unroll
            for (int n = 0; n < 8; ++n)
                acc_o[m][n] = __builtin_amdgcn_mfma_f32_16x16x32_bf16(A[m], B[n], acc_o[m][n], 0, 0, 0);
    };

    {
        bf16x8 aP[2], bP[8], aN[2], bN[8];
        lpv(0, aP, bP);
        #pragma unroll 2
        for (int kt = 0; kt < 16; kt += 2) {
            lpv(kt + 1, aN, bN);
            mpv(aP, bP);
            if (kt + 2 < 16) lpv(kt + 2, aP, bP);
            mpv(aN, bN);
        }
    }

    // ---- result scatter (nontemporal)
    float* obase = out + (long)b * NTOK * D_MODEL;
    #pragma unroll
    for (int m = 0; m < 2; ++m)
        #pragma unroll
        for (int rg = 0; rg < 4; ++rg) {
            const long tok = (long)s * SEG_W + off + 4L * (band * 32 + m * 16 + quad * 4 + rg);
            float* orow = obase + tok * D_MODEL + w * 128 + l16;
            #pragma unroll
            for (int n = 0; n < 8; ++n)
                __builtin_nontemporal_store(acc_o[m][n][rg], orow + n * 16);
        }

    // ---- fused zero-fill: 3 non-idx rows per q, full 1024 cols
    {
        const floatx4 z = {0.f, 0.f, 0.f, 0.f};
        const int chunk = tid & 255;     // float4 chunk within row
        const int half  = tid >> 8;      // 0..1
        #pragma unroll 4
        for (int p = 0; p < 48; ++p) {
            const int t = p * 2 + half;  // 0..95
            const int q = t / 3, e = t % 3;
            const int delta = e + (e >= off ? 1 : 0);
            const long tok = (long)s * SEG_W + 4L * (band * 32 + q) + delta;
            __builtin_nontemporal_store(z, (floatx4*)(obase + tok * D_MODEL + chunk * 4));
        }
    }
}

extern "C" void kernel_launch(void* const* d_in, const int* in_sizes, int n_in,
                              void* d_out, int out_size, void* d_ws, size_t ws_size,
                              hipStream_t stream) {
    const float* x   = (const float*)d_in[0];
    const int*   hid = (const int*)d_in[1];
    float*       out = (float*)d_out;
    bf16_t* xg  = (bf16_t*)d_ws;
    bf16_t* xgT = xg + XG_ELEMS;      // total ws: 33.6 MB (S eliminated)

    gather_kernel<<<dim3(2048), dim3(256), 0, stream>>>(x, hid, xg, xgT);
    attn_kernel<<<dim3(256), dim3(512), 0, stream>>>(xg, xgT, hid, out);
}

// Round 3
// 263.449 us; speedup vs baseline: 1.0949x; 1.0949x over previous
//
#include <hip/hip_runtime.h>
#include <hip/hip_bf16.h>

// DilatedAttention (b=4, n=8192, d=1024, w=2048, r=4):
// 16 independent 512x512 self-attentions at d=1024 over gathered tokens.
// alphas==1 (idx unique), so output = scatter(att) + zero-fill.
//
// R3: fused attention kernel rebuilt around async LDS staging (T3+T4).
// R2's direct global->VGPR fragment loads were latency-bound at LLC
// (~600cyc, depth-1 prefetch -> 6% MfmaUtil). Now: 3-buffer K/V panel
// pipeline via global_load_lds, counted s_waitcnt vmcnt(4) (2 panels
// always in flight, never drained in-loop), raw s_barrier + sched_barrier.
// Panels XOR-swizzled (slot = chunk ^ ((row>>2)&3)) -> 2-way LDS reads (free).
// LDS arena 128 KB: K 3x32K [0,96K) | red 2K [96K,98K) | P 32K [0,32K)
// | V 3x32K [32K,128K) - all overlaps phase-disjoint.

typedef __bf16 bf16_t;
typedef __bf16 bf16x8 __attribute__((ext_vector_type(8)));
typedef float floatx4 __attribute__((ext_vector_type(4)));

#define D_MODEL 1024
#define SEG_W   2048
#define RATE    4
#define M_SUB   512
#define NTOK    8192
#define NSEGT   16
#define XG_ELEMS ((long)NSEGT * M_SUB * D_MODEL)

__device__ __forceinline__ void gload16(const bf16_t* g, bf16_t* l) {
    __builtin_amdgcn_global_load_lds(
        (const __attribute__((address_space(1))) void*)g,
        (__attribute__((address_space(3))) void*)l, 16, 0, 0);
}

#define MFMA16(a, b, c) __builtin_amdgcn_mfma_f32_16x16x32_bf16((a), (b), (c), 0, 0, 0)

// ---------------------------------------------------------------------------
// K1: gather x[b, s*2048 + off + 4i, :] -> xg bf16 [seg][i][d]
//                                       -> xgT bf16 [seg][d][i]
// ---------------------------------------------------------------------------
__global__ __launch_bounds__(256) void gather_kernel(
    const float* __restrict__ x, const int* __restrict__ hidp,
    bf16_t* __restrict__ xg, bf16_t* __restrict__ xgT)
{
    const int off = ((hidp[0] % RATE) + RATE) % RATE;
    const int bid = blockIdx.x;
    const int seg = bid >> 7;
    const int rem = bid & 127;
    const int it  = rem >> 4;
    const int dt  = rem & 15;
    const int b   = seg >> 2, s = seg & 3;

    __shared__ ushort tile[64][65];

    const int t  = threadIdx.x;
    const int r  = t >> 2;
    const int cq = (t & 3) << 4;

    union U8 { bf16x8 v; ushort u[8]; };

    {
        const int  i   = it * 64 + r;
        const long tok = (long)s * SEG_W + off + 4L * i;
        const float* src = x + ((long)b * NTOK + tok) * D_MODEL + dt * 64 + cq;
        float4 f0 = ((const float4*)src)[0];
        float4 f1 = ((const float4*)src)[1];
        float4 f2 = ((const float4*)src)[2];
        float4 f3 = ((const float4*)src)[3];
        U8 lo, hi;
        lo.v[0]=(bf16_t)f0.x; lo.v[1]=(bf16_t)f0.y; lo.v[2]=(bf16_t)f0.z; lo.v[3]=(bf16_t)f0.w;
        lo.v[4]=(bf16_t)f1.x; lo.v[5]=(bf16_t)f1.y; lo.v[6]=(bf16_t)f1.z; lo.v[7]=(bf16_t)f1.w;
        hi.v[0]=(bf16_t)f2.x; hi.v[1]=(bf16_t)f2.y; hi.v[2]=(bf16_t)f2.z; hi.v[3]=(bf16_t)f2.w;
        hi.v[4]=(bf16_t)f3.x; hi.v[5]=(bf16_t)f3.y; hi.v[6]=(bf16_t)f3.z; hi.v[7]=(bf16_t)f3.w;
        bf16_t* dstg = xg + ((long)seg * M_SUB + i) * D_MODEL + dt * 64 + cq;
        *(bf16x8*)(dstg)     = lo.v;
        *(bf16x8*)(dstg + 8) = hi.v;
        #pragma unroll
        for (int j = 0; j < 8; ++j) { tile[r][cq + j] = lo.u[j]; tile[r][cq + 8 + j] = hi.u[j]; }
    }
    __syncthreads();
    {
        const int dc = r;
        const int iq = cq;
        U8 o0, o1;
        #pragma unroll
        for (int j = 0; j < 8; ++j) { o0.u[j] = tile[iq + j][dc]; o1.u[j] = tile[iq + 8 + j][dc]; }
        bf16_t* dstT = xgT + ((long)seg * D_MODEL + dt * 64 + dc) * M_SUB + it * 64 + iq;
        *(bf16x8*)(dstT)     = o0.v;
        *(bf16x8*)(dstT + 8) = o1.v;
    }
}

// ---------------------------------------------------------------------------
// K2: fused attention. One block = one (seg, 32-row q-band), 8 waves.
// QK: wave w owns cols w*64..+64; 32 K-panel tiles (BK=32), 3-buf pipeline.
// PV: two d-half passes; wave w owns d = p*512 + w*64..+64; 16 V-panel tiles.
// ---------------------------------------------------------------------------
__global__ __launch_bounds__(512, 2) void attn_kernel(
    const bf16_t* __restrict__ xg, const bf16_t* __restrict__ xgT,
    const int* __restrict__ hidp, float* __restrict__ out)
{
    const int off  = ((hidp[0] % RATE) + RATE) % RATE;
    const int bid0 = blockIdx.x;
    const int sub  = bid0 >> 3;
    const int seg  = (bid0 & 7) * 2 + (sub >> 4);   // seg->XCD locality
    const int band = sub & 15;
    const int b = seg >> 2, s = seg & 3;

    const int tid  = threadIdx.x;
    const int w    = tid >> 6;
    const int lane = tid & 63;
    const int l16  = lane & 15;
    const int quad = lane >> 4;

    __shared__ alignas(16) char arena[131072];      // 128 KB
    bf16_t* Pl = (bf16_t*)arena;                     // [0,32K) after QK dead
    float (*redmax)[32] = (float(*)[32])(arena + 98304);   // [96K,97K)
    float (*redsum)[32] = (float(*)[32])(arena + 99328);   // [97K,98K)

    const bf16_t* xs = xg + (long)seg * M_SUB * D_MODEL;

    // Q fragment row pointers (registers, L1-resident: shared by all 8 waves)
    const bf16_t* qr0 = xs + (long)(band * 32 + l16) * D_MODEL + quad * 8;
    const bf16_t* qr1 = qr0 + 16 * D_MODEL;

    // K panel staging: panel [512 tok][32 d], row 64B = 4x16B chunks.
    // lane -> (row = base + l>>2, chunk = l&3); src chunk pre-swizzled by
    // (row>>2)&3 == (l>>4) so LDS slot c holds global chunk c^((row>>2)&3).
    const bf16_t* ksrc = xs + (long)(w * 64 + (lane >> 2)) * D_MODEL
                            + (((lane & 3) ^ (lane >> 4)) * 8);
    auto stageK = [&](int buf, int t) {
        bf16_t* dst = (bf16_t*)arena + buf * 16384 + (w * 64) * 32;
        const bf16_t* src = ksrc + t * 32;
        #pragma unroll
        for (int j = 0; j < 4; ++j)
            gload16(src + j * 16 * D_MODEL, dst + j * 512);
    };

    // V panel staging: panel [512 d][32 tok], same geometry over xgT.
    const bf16_t* vsrc = xgT + ((long)seg * D_MODEL + w * 64 + (lane >> 2)) * M_SUB
                             + (((lane & 3) ^ (lane >> 4)) * 8);
    auto stageV = [&](int buf, int p, int t) {
        bf16_t* dst = (bf16_t*)(arena + 32768) + buf * 16384 + (w * 64) * 32;
        const bf16_t* src = vsrc + (long)p * 512 * M_SUB + t * 32;
        #pragma unroll
        for (int j = 0; j < 4; ++j)
            gload16(src + j * 16 * M_SUB, dst + j * 512);
    };

    const int rsw = (l16 >> 2) & 3;   // panel read swizzle key

    // ================= QK: 32 tiles of BK=32 =================
    floatx4 accS[2][4];
    #pragma unroll
    for (int m = 0; m < 2; ++m)
        #pragma unroll
        for (int n = 0; n < 4; ++n) accS[m][n] = (floatx4){0.f, 0.f, 0.f, 0.f};

    bf16x8 qe0, qe1, qo0, qo1;
    qe0 = *(const bf16x8*)qr0; qe1 = *(const bf16x8*)qr1;   // Q(0)
    stageK(0, 0); stageK(1, 1);

    #pragma unroll
    for (int t = 0; t < 32; ++t) {
        // vmcnt(4): my stage(t) landed; stage(t+1) [+Q prefetch] stay in flight
        if (t == 31) asm volatile("s_waitcnt vmcnt(0)");
        else         asm volatile("s_waitcnt vmcnt(4)");
        __builtin_amdgcn_s_barrier();        // all waves' stage(t) landed
        __builtin_amdgcn_sched_barrier(0);

        const bf16_t* Kb = (const bf16_t*)arena + (t % 3) * 16384;
        bf16x8 Bf[4];
        #pragma unroll
        for (int n = 0; n < 4; ++n) {
            const int row = w * 64 + n * 16 + l16;
            Bf[n] = *(const bf16x8*)&Kb[row * 32 + ((quad ^ rsw) * 8)];
        }
        if (t < 31) {       // Q(t+1) prefetch into the idle ping-pong set
            if (t & 1) { qe0 = *(const bf16x8*)(qr0 + (t + 1) * 32); qe1 = *(const bf16x8*)(qr1 + (t + 1) * 32); }
            else       { qo0 = *(const bf16x8*)(qr0 + (t + 1) * 32); qo1 = *(const bf16x8*)(qr1 + (t + 1) * 32); }
        }
        if (t < 30) stageK((t + 2) % 3, t + 2);

        const bf16x8 A0 = (t & 1) ? qo0 : qe0;
        const bf16x8 A1 = (t & 1) ? qo1 : qe1;
        #pragma unroll
        for (int n = 0; n < 4; ++n) {
            accS[0][n] = MFMA16(A0, Bf[n], accS[0][n]);
            accS[1][n] = MFMA16(A1, Bf[n], accS[1][n]);
        }
    }

    // ================= softmax (f32, cross-wave via LDS) =================
    #pragma unroll
    for (int m = 0; m < 2; ++m)
        #pragma unroll
        for (int n = 0; n < 4; ++n)
            #pragma unroll
            for (int rg = 0; rg < 4; ++rg) accS[m][n][rg] *= 0.03125f;  // 1/sqrt(1024)

    float mx[2][4];
    #pragma unroll
    for (int m = 0; m < 2; ++m)
        #pragma unroll
        for (int rg = 0; rg < 4; ++rg)
            mx[m][rg] = fmaxf(fmaxf(accS[m][0][rg], accS[m][1][rg]),
                              fmaxf(accS[m][2][rg], accS[m][3][rg]));
    #pragma unroll
    for (int d = 1; d < 16; d <<= 1)
        #pragma unroll
        for (int m = 0; m < 2; ++m)
            #pragma unroll
            for (int rg = 0; rg < 4; ++rg)
                mx[m][rg] = fmaxf(mx[m][rg], __shfl_xor(mx[m][rg], d, 64));
    if (l16 == 0) {
        #pragma unroll
        for (int m = 0; m < 2; ++m)
            #pragma unroll
            for (int rg = 0; rg < 4; ++rg)
                redmax[w][m * 16 + quad * 4 + rg] = mx[m][rg];
    }
    __syncthreads();
    float gm[2][4];
    #pragma unroll
    for (int m = 0; m < 2; ++m)
        #pragma unroll
        for (int rg = 0; rg < 4; ++rg) {
            const int row = m * 16 + quad * 4 + rg;
            float g = redmax[0][row];
            #pragma unroll
            for (int ww = 1; ww < 8; ++ww) g = fmaxf(g, redmax[ww][row]);
            gm[m][rg] = g;
        }
    float sm[2][4] = {{0.f,0.f,0.f,0.f},{0.f,0.f,0.f,0.f}};
    #pragma unroll
    for (int m = 0; m < 2; ++m)
        #pragma unroll
        for (int n = 0; n < 4; ++n)
            #pragma unroll
            for (int rg = 0; rg < 4; ++rg) {
                const float e = __expf(accS[m][n][rg] - gm[m][rg]);
                accS[m][n][rg] = e;
                sm[m][rg] += e;
            }
    #pragma unroll
    for (int d = 1; d < 16; d <<= 1)
        #pragma unroll
        for (int m = 0; m < 2; ++m)
            #pragma unroll
            for (int rg = 0; rg < 4; ++rg)
                sm[m][rg] += __shfl_xor(sm[m][rg], d, 64);
    if (l16 == 0) {
        #pragma unroll
        for (int m = 0; m < 2; ++m)
            #pragma unroll
            for (int rg = 0; rg < 4; ++rg)
                redsum[w][m * 16 + quad * 4 + rg] = sm[m][rg];
    }
    __syncthreads();
    float iv[2][4];
    #pragma unroll
    for (int m = 0; m < 2; ++m)
        #pragma unroll
        for (int rg = 0; rg < 4; ++rg) {
            const int row = m * 16 + quad * 4 + rg;
            float tt = redsum[0][row];
            #pragma unroll
            for (int ww = 1; ww < 8; ++ww) tt += redsum[ww][row];
            iv[m][rg] = 1.f / tt;
        }

    // ---- issue first V panels (overlap with P-store), then P -> LDS
    stageV(0, 0, 0); stageV(1, 0, 1);

    #pragma unroll
    for (int m = 0; m < 2; ++m)
        #pragma unroll
        for (int rg = 0; rg < 4; ++rg) {
            const int row = m * 16 + quad * 4 + rg;
            const float f = iv[m][rg];
            #pragma unroll
            for (int n = 0; n < 4; ++n) {
                const int col = w * 64 + n * 16 + l16;
                const int sw  = (((col >> 3) ^ (row & 7)) << 3) + (col & 7);
                Pl[row * 512 + sw] = (bf16_t)(accS[m][n][rg] * f);
            }
        }
    asm volatile("s_waitcnt lgkmcnt(0)");   // P visible (keeps V DMA in flight)
    __builtin_amdgcn_s_barrier();
    __builtin_amdgcn_sched_barrier(0);

    // ================= PV: 2 d-half passes x 16 tiles of 32 tokens =========
    floatx4 accA[2][4], accB[2][4];
    #pragma unroll
    for (int m = 0; m < 2; ++m)
        #pragma unroll
        for (int n = 0; n < 4; ++n) {
            accA[m][n] = (floatx4){0.f, 0.f, 0.f, 0.f};
            accB[m][n] = (floatx4){0.f, 0.f, 0.f, 0.f};
        }

    auto pv_pass = [&](int p, floatx4 (&acc)[2][4]) {
        #pragma unroll
        for (int t = 0; t < 16; ++t) {
            if (t == 15) asm volatile("s_waitcnt vmcnt(0)");
            else         asm volatile("s_waitcnt vmcnt(4)");
            __builtin_amdgcn_s_barrier();
            __builtin_amdgcn_sched_barrier(0);

            const bf16_t* Vb = (const bf16_t*)(arena + 32768) + (t % 3) * 16384;
            bf16x8 Af[2], Bf[4];
            const int ch = (t * 4 + quad) ^ (l16 & 7);
            #pragma unroll
            for (int m = 0; m < 2; ++m)
                Af[m] = *(const bf16x8*)&Pl[(m * 16 + l16) * 512 + ch * 8];
            #pragma unroll
            for (int n = 0; n < 4; ++n) {
                const int row = w * 64 + n * 16 + l16;
                Bf[n] = *(const bf16x8*)&Vb[row * 32 + ((quad ^ rsw) * 8)];
            }
            if (t < 14) stageV((t + 2) % 3, p, t + 2);
            #pragma unroll
            for (int m = 0; m < 2; ++m)
                #pragma unroll
                for (int n = 0; n < 4; ++n)
                    acc[m][n] = MFMA16(Af[m], Bf[n], acc[m][n]);
        }
    };

    pv_pass(0, accA);
    __builtin_amdgcn_s_barrier();           // all pass-A readers done
    __builtin_amdgcn_sched_barrier(0);
    stageV(0, 1, 0); stageV(1, 1, 1);
    pv_pass(1, accB);

    // ================= epilogue: scatter store + zero-fill =================
    float* obase = out + (long)b * NTOK * D_MODEL;
    #pragma unroll
    for (int m = 0; m < 2; ++m)
        #pragma unroll
        for (int rg = 0; rg < 4; ++rg) {
            const long tok = (long)s * SEG_W + off + 4L * (band * 32 + m * 16 + quad * 4 + rg);
            float* orow = obase + tok * D_MODEL;
            #pragma unroll
            for (int n = 0; n < 4; ++n) {
                const int d = w * 64 + n * 16 + l16;
                __builtin_nontemporal_store(accA[m][n][rg], orow + d);
                __builtin_nontemporal_store(accB[m][n][rg], orow + 512 + d);
            }
        }

    {
        const floatx4 z = {0.f, 0.f, 0.f, 0.f};
        const int chunk = tid & 255;
        const int half  = tid >> 8;
        #pragma unroll 4
        for (int p = 0; p < 48; ++p) {
            const int t = p * 2 + half;
            const int q = t / 3, e = t % 3;
            const int delta = e + (e >= off ? 1 : 0);
            const long tok = (long)s * SEG_W + 4L * (band * 32 + q) + delta;
            __builtin_nontemporal_store(z, (floatx4*)(obase + tok * D_MODEL + chunk * 4));
        }
    }
}

extern "C" void kernel_launch(void* const* d_in, const int* in_sizes, int n_in,
                              void* d_out, int out_size, void* d_ws, size_t ws_size,
                              hipStream_t stream) {
    const float* x   = (const float*)d_in[0];
    const int*   hid = (const int*)d_in[1];
    float*       out = (float*)d_out;
    bf16_t* xg  = (bf16_t*)d_ws;
    bf16_t* xgT = xg + XG_ELEMS;      // ws: 33.6 MB

    gather_kernel<<<dim3(2048), dim3(256), 0, stream>>>(x, hid, xg, xgT);
    attn_kernel<<<dim3(256), dim3(512), 0, stream>>>(xg, xgT, hid, out);
}

// Round 4
// 253.446 us; speedup vs baseline: 1.1382x; 1.0395x over previous
//
#include <hip/hip_runtime.h>
#include <hip/hip_bf16.h>

// DilatedAttention (b=4, n=8192, d=1024, w=2048, r=4):
// 16 independent 512x512 self-attentions at d=1024 over gathered tokens.
// alphas==1 (idx unique), so output = scatter(att) + zero-fill.
//
// R4: barrier-free free-running waves + deeper DMA rings.
// Key realization from R3 counters (MfmaUtil 7.9%, 90% stall): each wave
// stages and reads ONLY its own 64-row panel slice -> the per-tile
// s_barriers synchronized nothing and forced block-wide lockstep on the
// slowest DMA. Removed. Pipeline depth raised: K ring 4x32KB, sets
// (Q-pair + 4 gload_lds) issued 3 ahead, vmcnt(12) keeps 2 full sets in
// flight; V ring 3x32KB, 3 sets in flight, vmcnt(8), restage after MFMA.
// Cross-wave sync only where data is shared: softmax partials (2x
// __syncthreads) and the P panel (lgkmcnt(0)+s_barrier, V DMA stays live).
// LDS 130KB: QK: K[0,128K) | red[128K,130K) ; PV: P[0,32K) V[32K,128K)
// (K->P/V region reuse is protected by the softmax __syncthreads).

typedef __bf16 bf16_t;
typedef __bf16 bf16x8 __attribute__((ext_vector_type(8)));
typedef float floatx4 __attribute__((ext_vector_type(4)));

#define D_MODEL 1024
#define SEG_W   2048
#define RATE    4
#define M_SUB   512
#define NTOK    8192
#define NSEGT   16
#define XG_ELEMS ((long)NSEGT * M_SUB * D_MODEL)

__device__ __forceinline__ void gload16(const bf16_t* g, bf16_t* l) {
    __builtin_amdgcn_global_load_lds(
        (const __attribute__((address_space(1))) void*)g,
        (__attribute__((address_space(3))) void*)l, 16, 0, 0);
}

#define MFMA16(a, b, c) __builtin_amdgcn_mfma_f32_16x16x32_bf16((a), (b), (c), 0, 0, 0)

// ---------------------------------------------------------------------------
// K1: gather x[b, s*2048 + off + 4i, :] -> xg bf16 [seg][i][d]
//                                       -> xgT bf16 [seg][d][i]
// ---------------------------------------------------------------------------
__global__ __launch_bounds__(256) void gather_kernel(
    const float* __restrict__ x, const int* __restrict__ hidp,
    bf16_t* __restrict__ xg, bf16_t* __restrict__ xgT)
{
    const int off = ((hidp[0] % RATE) + RATE) % RATE;
    const int bid = blockIdx.x;
    const int seg = bid >> 7;
    const int rem = bid & 127;
    const int it  = rem >> 4;
    const int dt  = rem & 15;
    const int b   = seg >> 2, s = seg & 3;

    __shared__ ushort tile[64][65];

    const int t  = threadIdx.x;
    const int r  = t >> 2;
    const int cq = (t & 3) << 4;

    union U8 { bf16x8 v; ushort u[8]; };

    {
        const int  i   = it * 64 + r;
        const long tok = (long)s * SEG_W + off + 4L * i;
        const float* src = x + ((long)b * NTOK + tok) * D_MODEL + dt * 64 + cq;
        float4 f0 = ((const float4*)src)[0];
        float4 f1 = ((const float4*)src)[1];
        float4 f2 = ((const float4*)src)[2];
        float4 f3 = ((const float4*)src)[3];
        U8 lo, hi;
        lo.v[0]=(bf16_t)f0.x; lo.v[1]=(bf16_t)f0.y; lo.v[2]=(bf16_t)f0.z; lo.v[3]=(bf16_t)f0.w;
        lo.v[4]=(bf16_t)f1.x; lo.v[5]=(bf16_t)f1.y; lo.v[6]=(bf16_t)f1.z; lo.v[7]=(bf16_t)f1.w;
        hi.v[0]=(bf16_t)f2.x; hi.v[1]=(bf16_t)f2.y; hi.v[2]=(bf16_t)f2.z; hi.v[3]=(bf16_t)f2.w;
        hi.v[4]=(bf16_t)f3.x; hi.v[5]=(bf16_t)f3.y; hi.v[6]=(bf16_t)f3.z; hi.v[7]=(bf16_t)f3.w;
        bf16_t* dstg = xg + ((long)seg * M_SUB + i) * D_MODEL + dt * 64 + cq;
        *(bf16x8*)(dstg)     = lo.v;
        *(bf16x8*)(dstg + 8) = hi.v;
        #pragma unroll
        for (int j = 0; j < 8; ++j) { tile[r][cq + j] = lo.u[j]; tile[r][cq + 8 + j] = hi.u[j]; }
    }
    __syncthreads();
    {
        const int dc = r;
        const int iq = cq;
        U8 o0, o1;
        #pragma unroll
        for (int j = 0; j < 8; ++j) { o0.u[j] = tile[iq + j][dc]; o1.u[j] = tile[iq + 8 + j][dc]; }
        bf16_t* dstT = xgT + ((long)seg * D_MODEL + dt * 64 + dc) * M_SUB + it * 64 + iq;
        *(bf16x8*)(dstT)     = o0.v;
        *(bf16x8*)(dstT + 8) = o1.v;
    }
}

// ---------------------------------------------------------------------------
// K2: fused attention. One block = one (seg, 32-row q-band), 8 waves.
// Waves free-run (no per-tile barriers): every panel slice is per-wave.
// ---------------------------------------------------------------------------
__global__ __launch_bounds__(512, 2) void attn_kernel(
    const bf16_t* __restrict__ xg, const bf16_t* __restrict__ xgT,
    const int* __restrict__ hidp, float* __restrict__ out)
{
    const int off  = ((hidp[0] % RATE) + RATE) % RATE;
    const int bid0 = blockIdx.x;
    const int sub  = bid0 >> 3;
    const int seg  = (bid0 & 7) * 2 + (sub >> 4);   // seg->XCD locality
    const int band = sub & 15;
    const int b = seg >> 2, s = seg & 3;

    const int tid  = threadIdx.x;
    const int w    = tid >> 6;
    const int lane = tid & 63;
    const int l16  = lane & 15;
    const int quad = lane >> 4;

    __shared__ alignas(16) char arena[133120];           // 130 KB
    bf16_t* Kring = (bf16_t*)arena;                      // QK: 4 x 32K [0,128K)
    float (*redmax)[32] = (float(*)[32])(arena + 131072);  // [128K,129K)
    float (*redsum)[32] = (float(*)[32])(arena + 132096);  // [129K,130K)
    bf16_t* Pl    = (bf16_t*)arena;                      // PV: [0,32K)
    bf16_t* Vring = (bf16_t*)(arena + 32768);            // PV: 3 x 32K [32K,128K)

    const bf16_t* xs = xg + (long)seg * M_SUB * D_MODEL;

    // Q fragment row pointers (identical rows for all 8 waves -> L1 hits)
    const bf16_t* qr0 = xs + (long)(band * 32 + l16) * D_MODEL + quad * 8;
    const bf16_t* qr1 = qr0 + 16 * D_MODEL;

    // K panel staging: panel [512 tok][32 d]; wave w stages (and later reads)
    // ONLY rows [w*64, w*64+64). Chunk pre-swizzle: LDS slot c holds global
    // chunk c ^ ((row>>2)&3).
    const bf16_t* ksrc = xs + (long)(w * 64 + (lane >> 2)) * D_MODEL
                            + (((lane & 3) ^ (lane >> 4)) * 8);
    auto stageK = [&](int buf, int t) {
        bf16_t* dst = Kring + buf * 16384 + (w * 64) * 32;
        const bf16_t* src = ksrc + t * 32;
        #pragma unroll
        for (int j = 0; j < 4; ++j)
            gload16(src + j * 16 * D_MODEL, dst + j * 512);
    };

    // V panel staging: panel [512 d][32 tok] over xgT, same per-wave slicing.
    const bf16_t* vsrc = xgT + ((long)seg * D_MODEL + w * 64 + (lane >> 2)) * M_SUB
                             + (((lane & 3) ^ (lane >> 4)) * 8);
    auto stageV = [&](int buf, int p, int t) {
        bf16_t* dst = Vring + buf * 16384 + (w * 64) * 32;
        const bf16_t* src = vsrc + (long)p * 512 * M_SUB + t * 32;
        #pragma unroll
        for (int j = 0; j < 4; ++j)
            gload16(src + j * 16 * M_SUB, dst + j * 512);
    };

    const int rsw = (l16 >> 2) & 3;   // panel read swizzle key

    // ================= QK: 32 tiles of BK=32, ring-4, 3 sets ahead ========
    floatx4 accS[2][4];
    #pragma unroll
    for (int m = 0; m < 2; ++m)
        #pragma unroll
        for (int n = 0; n < 4; ++n) accS[m][n] = (floatx4){0.f, 0.f, 0.f, 0.f};

    bf16x8 qf[4][2];
    #pragma unroll
    for (int p0 = 0; p0 < 3; ++p0) {        // prologue: sets 0..2 (6 vmem each)
        qf[p0][0] = *(const bf16x8*)(qr0 + p0 * 32);
        qf[p0][1] = *(const bf16x8*)(qr1 + p0 * 32);
        stageK(p0, p0);
    }

    #pragma unroll
    for (int t = 0; t < 32; ++t) {
        // set = {2 Q loads, 4 stage loads} issued in order; keeping the 12
        // newest (2 sets) guarantees set t (Q(t) + stage(t)) has landed.
        if (t <= 29)      asm volatile("s_waitcnt vmcnt(12)" ::: "memory");
        else if (t == 30) asm volatile("s_waitcnt vmcnt(6)"  ::: "memory");
        else              asm volatile("s_waitcnt vmcnt(0)"  ::: "memory");

        const bf16_t* Kb = Kring + (t & 3) * 16384;
        bf16x8 Bf[4];
        #pragma unroll
        for (int n = 0; n < 4; ++n) {
            const int row = w * 64 + n * 16 + l16;
            Bf[n] = *(const bf16x8*)&Kb[row * 32 + ((quad ^ rsw) * 8)];
        }
        if (t <= 28) {          // issue set t+3 (buf (t+3)&3: reads retired at t-1)
            qf[(t + 3) & 3][0] = *(const bf16x8*)(qr0 + (t + 3) * 32);
            qf[(t + 3) & 3][1] = *(const bf16x8*)(qr1 + (t + 3) * 32);
            stageK((t + 3) & 3, t + 3);
        }
        #pragma unroll
        for (int n = 0; n < 4; ++n) {
            accS[0][n] = MFMA16(qf[t & 3][0], Bf[n], accS[0][n]);
            accS[1][n] = MFMA16(qf[t & 3][1], Bf[n], accS[1][n]);
        }
    }

    // ================= softmax (f32, cross-wave via LDS) =================
    #pragma unroll
    for (int m = 0; m < 2; ++m)
        #pragma unroll
        for (int n = 0; n < 4; ++n)
            #pragma unroll
            for (int rg = 0; rg < 4; ++rg) accS[m][n][rg] *= 0.03125f;  // 1/sqrt(1024)

    float mx[2][4];
    #pragma unroll
    for (int m = 0; m < 2; ++m)
        #pragma unroll
        for (int rg = 0; rg < 4; ++rg)
            mx[m][rg] = fmaxf(fmaxf(accS[m][0][rg], accS[m][1][rg]),
                              fmaxf(accS[m][2][rg], accS[m][3][rg]));
    #pragma unroll
    for (int d = 1; d < 16; d <<= 1)
        #pragma unroll
        for (int m = 0; m < 2; ++m)
            #pragma unroll
            for (int rg = 0; rg < 4; ++rg)
                mx[m][rg] = fmaxf(mx[m][rg], __shfl_xor(mx[m][rg], d, 64));
    if (l16 == 0) {
        #pragma unroll
        for (int m = 0; m < 2; ++m)
            #pragma unroll
            for (int rg = 0; rg < 4; ++rg)
                redmax[w][m * 16 + quad * 4 + rg] = mx[m][rg];
    }
    __syncthreads();
    float gm[2][4];
    #pragma unroll
    for (int m = 0; m < 2; ++m)
        #pragma unroll
        for (int rg = 0; rg < 4; ++rg) {
            const int row = m * 16 + quad * 4 + rg;
            float g = redmax[0][row];
            #pragma unroll
            for (int ww = 1; ww < 8; ++ww) g = fmaxf(g, redmax[ww][row]);
            gm[m][rg] = g;
        }
    float sm[2][4] = {{0.f,0.f,0.f,0.f},{0.f,0.f,0.f,0.f}};
    #pragma unroll
    for (int m = 0; m < 2; ++m)
        #pragma unroll
        for (int n = 0; n < 4; ++n)
            #pragma unroll
            for (int rg = 0; rg < 4; ++rg) {
                const float e = __expf(accS[m][n][rg] - gm[m][rg]);
                accS[m][n][rg] = e;
                sm[m][rg] += e;
            }
    #pragma unroll
    for (int d = 1; d < 16; d <<= 1)
        #pragma unroll
        for (int m = 0; m < 2; ++m)
            #pragma unroll
            for (int rg = 0; rg < 4; ++rg)
                sm[m][rg] += __shfl_xor(sm[m][rg], d, 64);
    if (l16 == 0) {
        #pragma unroll
        for (int m = 0; m < 2; ++m)
            #pragma unroll
            for (int rg = 0; rg < 4; ++rg)
                redsum[w][m * 16 + quad * 4 + rg] = sm[m][rg];
    }
    __syncthreads();
    float iv[2][4];
    #pragma unroll
    for (int m = 0; m < 2; ++m)
        #pragma unroll
        for (int rg = 0; rg < 4; ++rg) {
            const int row = m * 16 + quad * 4 + rg;
            float tt = redsum[0][row];
            #pragma unroll
            for (int ww = 1; ww < 8; ++ww) tt += redsum[ww][row];
            iv[m][rg] = 1.f / tt;
        }

    // ---- issue first 3 V sets (overlap with P-store), then P -> LDS
    stageV(0, 0, 0); stageV(1, 0, 1); stageV(2, 0, 2);

    #pragma unroll
    for (int m = 0; m < 2; ++m)
        #pragma unroll
        for (int rg = 0; rg < 4; ++rg) {
            const int row = m * 16 + quad * 4 + rg;
            const float f = iv[m][rg];
            #pragma unroll
            for (int n = 0; n < 4; ++n) {
                const int col = w * 64 + n * 16 + l16;
                const int sw  = (((col >> 3) ^ (row & 7)) << 3) + (col & 7);
                Pl[row * 512 + sw] = (bf16_t)(accS[m][n][rg] * f);
            }
        }
    asm volatile("s_waitcnt lgkmcnt(0)" ::: "memory");  // P visible; V DMA live
    __builtin_amdgcn_s_barrier();
    __builtin_amdgcn_sched_barrier(0);

    // ================= PV: 2 d-half passes x 16 tiles, ring-3 =============
    floatx4 accA[2][4], accB[2][4];
    #pragma unroll
    for (int m = 0; m < 2; ++m)
        #pragma unroll
        for (int n = 0; n < 4; ++n) {
            accA[m][n] = (floatx4){0.f, 0.f, 0.f, 0.f};
            accB[m][n] = (floatx4){0.f, 0.f, 0.f, 0.f};
        }

    auto pv_pass = [&](int p, floatx4 (&acc)[2][4]) {
        #pragma unroll
        for (int t = 0; t < 16; ++t) {
            // V sets = 4 loads; 3 sets in flight; keep 8 newest -> set t done
            if (t <= 13)      asm volatile("s_waitcnt vmcnt(8)" ::: "memory");
            else if (t == 14) asm volatile("s_waitcnt vmcnt(4)" ::: "memory");
            else              asm volatile("s_waitcnt vmcnt(0)" ::: "memory");

            const bf16_t* Vb = Vring + (t % 3) * 16384;
            bf16x8 Af[2], Bf[4];
            const int ch = (t * 4 + quad) ^ (l16 & 7);
            #pragma unroll
            for (int m = 0; m < 2; ++m)
                Af[m] = *(const bf16x8*)&Pl[(m * 16 + l16) * 512 + ch * 8];
            #pragma unroll
            for (int n = 0; n < 4; ++n) {
                const int row = w * 64 + n * 16 + l16;
                Bf[n] = *(const bf16x8*)&Vb[row * 32 + ((quad ^ rsw) * 8)];
            }
            #pragma unroll
            for (int m = 0; m < 2; ++m)
                #pragma unroll
                for (int n = 0; n < 4; ++n)
                    acc[m][n] = MFMA16(Af[m], Bf[n], acc[m][n]);
            // restage buf t%3 AFTER the MFMAs: this iteration's ds_reads of
            // that buffer are retired by the compiler's lgkm wait before them.
            if (t <= 12) stageV(t % 3, p, t + 3);
        }
    };

    pv_pass(0, accA);
    // pass A drained to vmcnt(0) at its t=15; all its V reads are retired.
    stageV(0, 1, 0); stageV(1, 1, 1); stageV(2, 1, 2);
    pv_pass(1, accB);

    // ================= epilogue: scatter store + zero-fill =================
    float* obase = out + (long)b * NTOK * D_MODEL;
    #pragma unroll
    for (int m = 0; m < 2; ++m)
        #pragma unroll
        for (int rg = 0; rg < 4; ++rg) {
            const long tok = (long)s * SEG_W + off + 4L * (band * 32 + m * 16 + quad * 4 + rg);
            float* orow = obase + tok * D_MODEL;
            #pragma unroll
            for (int n = 0; n < 4; ++n) {
                const int d = w * 64 + n * 16 + l16;
                __builtin_nontemporal_store(accA[m][n][rg], orow + d);
                __builtin_nontemporal_store(accB[m][n][rg], orow + 512 + d);
            }
        }

    {
        const floatx4 z = {0.f, 0.f, 0.f, 0.f};
        const int chunk = tid & 255;
        const int half  = tid >> 8;
        #pragma unroll 4
        for (int p = 0; p < 48; ++p) {
            const int t = p * 2 + half;
            const int q = t / 3, e = t % 3;
            const int delta = e + (e >= off ? 1 : 0);
            const long tok = (long)s * SEG_W + 4L * (band * 32 + q) + delta;
            __builtin_nontemporal_store(z, (floatx4*)(obase + tok * D_MODEL + chunk * 4));
        }
    }
}

extern "C" void kernel_launch(void* const* d_in, const int* in_sizes, int n_in,
                              void* d_out, int out_size, void* d_ws, size_t ws_size,
                              hipStream_t stream) {
    const float* x   = (const float*)d_in[0];
    const int*   hid = (const int*)d_in[1];
    float*       out = (float*)d_out;
    bf16_t* xg  = (bf16_t*)d_ws;
    bf16_t* xgT = xg + XG_ELEMS;      // ws: 33.6 MB

    gather_kernel<<<dim3(2048), dim3(256), 0, stream>>>(x, hid, xg, xgT);
    attn_kernel<<<dim3(256), dim3(512), 0, stream>>>(xg, xgT, hid, out);
}